// Round 2
// baseline (327.822 us; speedup 1.0000x reference)
//
#include <hip/hip_runtime.h>

#define N_EMB 65536
#define DIM   512
#define K_C   256
#define ROWS  128   // rows per block
#define NCHUNK (DIM / 32)

// ws layout: cbh = frag-ordered bf16-hi centroids (256 KiB) | cnorm = float[256] (1 KiB)

typedef __attribute__((ext_vector_type(4))) float        f32x4;
typedef __attribute__((ext_vector_type(8))) __bf16       bf16x8;
typedef __attribute__((ext_vector_type(8))) short        s16x8;
typedef __attribute__((ext_vector_type(4))) unsigned int u32x4;

// ---- MFMA wrapper (round-1 verified). Primary: v8bf16; SFINAE fallback v8i16.
template <class T>
__device__ inline auto mfma_bf16_t(T a, T b, f32x4 c, int)
    -> decltype(__builtin_amdgcn_mfma_f32_16x16x32_bf16(a, b, c, 0, 0, 0)) {
  return __builtin_amdgcn_mfma_f32_16x16x32_bf16(a, b, c, 0, 0, 0);
}
template <class T>
__device__ inline f32x4 mfma_bf16_t(T a, T b, f32x4 c, long) {
  return __builtin_amdgcn_mfma_f32_16x16x32_bf16(
      __builtin_bit_cast(s16x8, a), __builtin_bit_cast(s16x8, b), c, 0, 0, 0);
}
__device__ inline f32x4 MFMA(bf16x8 a, bf16x8 b, f32x4 c) {
  return mfma_bf16_t(a, b, c, 0);
}

__device__ inline unsigned umin_(unsigned a, unsigned b) { return a < b ? a : b; }
__device__ inline unsigned umax_(unsigned a, unsigned b) { return a > b ? a : b; }

// 8 fp32 -> 8 (bf16 hi, bf16 lo) pairs, RNE both.  x ~= hi + lo.
__device__ inline void cvt8(const float4 a, const float4 b, u32x4& hw, u32x4& lw) {
  float v[8] = {a.x, a.y, a.z, a.w, b.x, b.y, b.z, b.w};
  unsigned h[8], l[8];
#pragma unroll
  for (int i = 0; i < 8; ++i) {
    const unsigned u  = __float_as_uint(v[i]);
    const unsigned hb = (u + 0x7FFFu + ((u >> 16) & 1u)) >> 16;
    h[i] = hb;
    const float hf = __uint_as_float(hb << 16);
    const unsigned ul = __float_as_uint(v[i] - hf);
    l[i] = (ul + 0x7FFFu + ((ul >> 16) & 1u)) >> 16;
  }
  hw = (u32x4){h[0] | (h[1] << 16), h[2] | (h[3] << 16),
               h[4] | (h[5] << 16), h[6] | (h[7] << 16)};
  lw = (u32x4){l[0] | (l[1] << 16), l[2] | (l[3] << 16),
               l[4] | (l[5] << 16), l[6] | (l[7] << 16)};
}

__device__ inline u32x4 cvt8hi(const float4 a, const float4 b) {
  float v[8] = {a.x, a.y, a.z, a.w, b.x, b.y, b.z, b.w};
  unsigned h[8];
#pragma unroll
  for (int i = 0; i < 8; ++i) {
    const unsigned u = __float_as_uint(v[i]);
    h[i] = (u + 0x7FFFu + ((u >> 16) & 1u)) >> 16;
  }
  return (u32x4){h[0] | (h[1] << 16), h[2] | (h[3] << 16),
                 h[4] | (h[5] << 16), h[6] | (h[7] << 16)};
}

// ---- prep (fused): pack centroids to frag-ordered bf16-hi + exact fp32 norms.
// Frag element: lane L of [chunk][ct] block holds C[ct*16+(L&15)][chunk*32+(L>>4)*8+j].
__global__ void pack_centroids(const float* __restrict__ cent,
                               unsigned* __restrict__ cbh,
                               float* __restrict__ cnorm) {
  const int k    = blockIdx.x;   // centroid
  const int lane = threadIdx.x;  // 0..63, dims lane*8..+7
  const float* src = cent + (size_t)k * DIM + lane * 8;
  const float4 a = *(const float4*)src;
  const float4 b = *(const float4*)(src + 4);
  const int chunk = lane >> 2, g = lane & 3;
  ((u32x4*)cbh)[((size_t)chunk * 16 + (k >> 4)) * 64 + g * 16 + (k & 15)] =
      cvt8hi(a, b);
  float s = a.x * a.x + a.y * a.y + a.z * a.z + a.w * a.w +
            b.x * b.x + b.y * b.y + b.z * b.z + b.w * b.w;
#pragma unroll
  for (int off = 32; off > 0; off >>= 1) s += __shfl_down(s, off, 64);
  if (lane == 0) cnorm[k] = s;
}

// ---- main: 128 rows x 256 centroids per block, 256 threads (4 waves x 2 row-tiles).
// dot(e,c) ~ (eh+el)*ch via 2 chained MFMA (score err sigma ~0.02 << spacing ~12).
// Approx top-4/row in registers, exact fp32 rescore (4 cand x 16 lanes) + gather.
__global__ __launch_bounds__(256, 2)
void neg_sampler_main(const float* __restrict__ emb,
                      const float* __restrict__ cent,
                      const unsigned* __restrict__ cbh,
                      const float* __restrict__ cnorm,
                      float* __restrict__ out) {
  extern __shared__ char lds[];
  char* const EH = lds;           //  8 KiB: E-hi frags, 8 row-tiles x 1 KiB
  char* const EL = lds + 8192;    //  8 KiB: E-lo frags
  char* const CB = lds + 16384;   // 16 KiB: C-hi frags, 16 ct-tiles x 1 KiB

  const int tid  = threadIdx.x;
  const int lane = tid & 63;
  const int w    = tid >> 6;              // wave 0..3 -> row tiles 2w, 2w+1
  const int row0 = blockIdx.x * ROWS;

  f32x4 acc[2][16];
#pragma unroll
  for (int i = 0; i < 2; ++i)
#pragma unroll
    for (int j = 0; j < 16; ++j) acc[i][j] = (f32x4){0.f, 0.f, 0.f, 0.f};

  // E staging: thread handles row er, dim-groups g0, g0+1 (16 contiguous dims).
  const int er = tid & 127;
  const int g0 = (tid >> 7) * 2;  // 0 or 2
  const float* const ebase = emb + (size_t)(row0 + er) * DIM;
  const int et = er >> 4, erow = er & 15;
  const int eoffA = et * 1024 + (g0 * 16 + erow) * 16;
  const int eoffB = et * 1024 + ((g0 + 1) * 16 + erow) * 16;

  float4 ev0, ev1, ev2, ev3;  // next-chunk E (16 dims)
  u32x4  cv0, cv1, cv2, cv3;  // next-chunk C-hi frags (linear copy)

  auto load_chunk = [&](int c) {
    const float* p0 = ebase + c * 32 + g0 * 8;
    ev0 = *(const float4*)p0;
    ev1 = *(const float4*)(p0 + 4);
    ev2 = *(const float4*)(p0 + 8);
    ev3 = *(const float4*)(p0 + 12);
    const u32x4* cs = (const u32x4*)cbh + (size_t)c * 1024 + tid;
    cv0 = cs[0]; cv1 = cs[256]; cv2 = cs[512]; cv3 = cs[768];
  };
  auto store_chunk = [&]() {
    u32x4 hw, lw;
    cvt8(ev0, ev1, hw, lw);
    *(u32x4*)(EH + eoffA) = hw; *(u32x4*)(EL + eoffA) = lw;
    cvt8(ev2, ev3, hw, lw);
    *(u32x4*)(EH + eoffB) = hw; *(u32x4*)(EL + eoffB) = lw;
    u32x4* cd = (u32x4*)CB + tid;
    cd[0] = cv0; cd[256] = cv1; cd[512] = cv2; cd[768] = cv3;
  };

  load_chunk(0);
  for (int c = 0; c < NCHUNK; ++c) {
    if (c) __syncthreads();          // all reads of LDS(c-1) done before overwrite
    store_chunk();                   // cvt + ds_write (auto-waits own vmem loads)
    if (c < NCHUNK - 1) load_chunk(c + 1);  // prefetch survives raw barrier
    asm volatile("s_waitcnt lgkmcnt(0)" ::: "memory");
    __builtin_amdgcn_sched_barrier(0);
    __builtin_amdgcn_s_barrier();    // raw: no vmcnt(0) drain
    asm volatile("" ::: "memory");

    const char* ehp = EH + (2 * w) * 1024 + lane * 16;
    const char* elp = EL + (2 * w) * 1024 + lane * 16;
    const bf16x8 eh0 = *(const bf16x8*)ehp;
    const bf16x8 eh1 = *(const bf16x8*)(ehp + 1024);
    const bf16x8 el0 = *(const bf16x8*)elp;
    const bf16x8 el1 = *(const bf16x8*)(elp + 1024);
    const char* cbp = CB + lane * 16;
#pragma unroll
    for (int ct = 0; ct < 16; ++ct) {
      const bf16x8 ch = *(const bf16x8*)(cbp + ct * 1024);
      acc[0][ct] = MFMA(eh0, ch, acc[0][ct]);
      acc[1][ct] = MFMA(eh1, ch, acc[1][ct]);
      acc[0][ct] = MFMA(el0, ch, acc[0][ct]);
      acc[1][ct] = MFMA(el1, ch, acc[1][ct]);
    }
  }
  __syncthreads();

  // ---- approx top-4 per row. D tile mapping: row=(lane>>4)*4+reg, col=lane&15.
  unsigned* top4 = (unsigned*)lds;  // [128][4], reuses EH region
  const int lgrp = lane >> 4, lcol = lane & 15;
  float cnv[16];
#pragma unroll
  for (int ct = 0; ct < 16; ++ct) cnv[ct] = cnorm[ct * 16 + lcol];

#pragma unroll
  for (int rt = 0; rt < 2; ++rt) {
#pragma unroll
    for (int rg = 0; rg < 4; ++rg) {
      unsigned b0 = 0xFFFFFFFFu, b1 = b0, b2 = b0, b3 = b0;
      auto ins = [&](unsigned u) {
        b3 = umin_(b3, umax_(b2, u));
        b2 = umin_(b2, umax_(b1, u));
        b1 = umin_(b1, umax_(b0, u));
        b0 = umin_(b0, u);
      };
#pragma unroll
      for (int ct = 0; ct < 16; ++ct) {
        const float s = fmaf(-2.f, acc[rt][ct][rg], cnv[ct]);  // ||e||^2 drops
        ins((__float_as_uint(s) & 0xFFFFFF00u) | (unsigned)(ct * 16 + lcol));
      }
#pragma unroll
      for (int off = 1; off < 16; off <<= 1) {  // merge 16 col-lanes of the group
        const unsigned o0 = __shfl_xor(b0, off, 64);
        const unsigned o1 = __shfl_xor(b1, off, 64);
        const unsigned o2 = __shfl_xor(b2, off, 64);
        const unsigned o3 = __shfl_xor(b3, off, 64);
        ins(o0); ins(o1); ins(o2); ins(o3);
      }
      if (lcol == 0) {
        const int row = w * 32 + rt * 16 + lgrp * 4 + rg;
        *(u32x4*)(top4 + row * 4) = (u32x4){b0, b1, b2, b3};
      }
    }
  }
  __syncthreads();

  // ---- exact fp32 rescore: 4 candidates x 16 lanes each, then exact 2nd-min.
  for (int rr = 0; rr < 32; ++rr) {
    const int row  = w * 32 + rr;
    const int grow = row0 + row;
    const unsigned t0 = top4[row * 4 + 0], t1 = top4[row * 4 + 1];
    const unsigned t2 = top4[row * 4 + 2], t3 = top4[row * 4 + 3];
    const int c0 = (int)(t0 & 0xFFu), c1 = (int)(t1 & 0xFFu);
    const int c2 = (int)(t2 & 0xFFu), c3 = (int)(t3 & 0xFFu);
    const int cj = lane >> 4, li = lane & 15;
    const int myc = cj == 0 ? c0 : cj == 1 ? c1 : cj == 2 ? c2 : c3;

    const float4* e4 = (const float4*)(emb + (size_t)grow * DIM);
    const float4* c4 = (const float4*)(cent + (size_t)myc * DIM);
    float d = 0.f;
#pragma unroll
    for (int i = 0; i < 8; ++i) {
      const float4 ev = e4[li + 16 * i];
      const float4 cv = c4[li + 16 * i];
      d = fmaf(ev.x, cv.x, d); d = fmaf(ev.y, cv.y, d);
      d = fmaf(ev.z, cv.z, d); d = fmaf(ev.w, cv.w, d);
    }
#pragma unroll
    for (int off = 1; off < 16; off <<= 1) d += __shfl_xor(d, off, 64);

    const float s0 = fmaf(-2.f, __shfl(d, 0, 64),  cnorm[c0]);
    const float s1 = fmaf(-2.f, __shfl(d, 16, 64), cnorm[c1]);
    const float s2 = fmaf(-2.f, __shfl(d, 32, 64), cnorm[c2]);
    const float s3 = fmaf(-2.f, __shfl(d, 48, 64), cnorm[c3]);

    float v1 = s0, v2 = 3.4e38f;
    int i1 = c0, i2 = K_C;
    auto upd = [&](float s, int c) {  // stable smaller-index tiebreak
      if (s < v1 || (s == v1 && c < i1)) { v2 = v1; i2 = i1; v1 = s; i1 = c; }
      else if (s < v2 || (s == v2 && c < i2)) { v2 = s; i2 = c; }
    };
    upd(s1, c1); upd(s2, c2); upd(s3, c3);

    const float4* sp = (const float4*)(cent + (size_t)i2 * DIM) + lane * 2;
    float4* op = (float4*)(out + (size_t)grow * DIM) + lane * 2;
    op[0] = sp[0];
    op[1] = sp[1];
  }
}

extern "C" void kernel_launch(void* const* d_in, const int* in_sizes, int n_in,
                              void* d_out, int out_size, void* d_ws, size_t ws_size,
                              hipStream_t stream) {
  const float* emb  = (const float*)d_in[0];
  const float* cent = (const float*)d_in[1];
  // d_in[2] = batch_id, unused.
  unsigned* cbh = (unsigned*)d_ws;                     // 256 KiB frag-ordered C-hi
  float* cnorm  = (float*)((char*)d_ws + 256 * 1024);  // 1 KiB

  pack_centroids<<<K_C, 64, 0, stream>>>(cent, cbh, cnorm);
  neg_sampler_main<<<N_EMB / ROWS, 256, 32768, stream>>>(emb, cent, cbh, cnorm,
                                                         (float*)d_out);
}

// Round 4
// 325.540 us; speedup vs baseline: 1.0070x; 1.0070x over previous
//
#include <hip/hip_runtime.h>

#define N_EMB 65536
#define DIM   512
#define K_C   256
#define NCHUNK (DIM / 32)

// ws layout: cbh = frag-ordered bf16-hi centroids (256 KiB) | cnorm = float[256] (1 KiB)

typedef __attribute__((ext_vector_type(4))) float        f32x4;
typedef __attribute__((ext_vector_type(8))) __bf16       bf16x8;
typedef __attribute__((ext_vector_type(8))) short        s16x8;
typedef __attribute__((ext_vector_type(4))) unsigned int u32x4;

// ---- MFMA wrapper (rounds 1-2 verified). Primary: v8bf16; SFINAE fallback v8i16.
template <class T>
__device__ inline auto mfma_bf16_t(T a, T b, f32x4 c, int)
    -> decltype(__builtin_amdgcn_mfma_f32_16x16x32_bf16(a, b, c, 0, 0, 0)) {
  return __builtin_amdgcn_mfma_f32_16x16x32_bf16(a, b, c, 0, 0, 0);
}
template <class T>
__device__ inline f32x4 mfma_bf16_t(T a, T b, f32x4 c, long) {
  return __builtin_amdgcn_mfma_f32_16x16x32_bf16(
      __builtin_bit_cast(s16x8, a), __builtin_bit_cast(s16x8, b), c, 0, 0, 0);
}
__device__ inline f32x4 MFMA(bf16x8 a, bf16x8 b, f32x4 c) {
  return mfma_bf16_t(a, b, c, 0);
}

__device__ inline unsigned umin_(unsigned a, unsigned b) { return a < b ? a : b; }
__device__ inline unsigned umax_(unsigned a, unsigned b) { return a > b ? a : b; }

// Truncation split: 8 fp32 -> packed bf16 hi + bf16 lo.  x ~= hi + lo, |resid| <
// 2^-16|x|.  Cheap (~5 VALU/elem); e-side split error is negligible vs the
// dropped c_lo term (sigma ~0.03 << spacing ~12); exact rescore fixes the rest.
__device__ inline void split8(const float4 a, const float4 b, u32x4& hw, u32x4& lw) {
  const float v[8] = {a.x, a.y, a.z, a.w, b.x, b.y, b.z, b.w};
  unsigned hp[4], lp[4];
#pragma unroll
  for (int i = 0; i < 4; ++i) {
    const unsigned u0 = __float_as_uint(v[2 * i]);
    const unsigned u1 = __float_as_uint(v[2 * i + 1]);
    hp[i] = (u0 >> 16) | (u1 & 0xFFFF0000u);
    const float r0 = v[2 * i]     - __uint_as_float(u0 & 0xFFFF0000u);
    const float r1 = v[2 * i + 1] - __uint_as_float(u1 & 0xFFFF0000u);
    lp[i] = (__float_as_uint(r0) >> 16) | (__float_as_uint(r1) & 0xFFFF0000u);
  }
  hw = (u32x4){hp[0], hp[1], hp[2], hp[3]};
  lw = (u32x4){lp[0], lp[1], lp[2], lp[3]};
}

__device__ inline u32x4 cvt8hi(const float4 a, const float4 b) {
  float v[8] = {a.x, a.y, a.z, a.w, b.x, b.y, b.z, b.w};
  unsigned h[8];
#pragma unroll
  for (int i = 0; i < 8; ++i) {  // RNE for centroids (prep is cheap, keep quality)
    const unsigned u = __float_as_uint(v[i]);
    h[i] = (u + 0x7FFFu + ((u >> 16) & 1u)) >> 16;
  }
  return (u32x4){h[0] | (h[1] << 16), h[2] | (h[3] << 16),
                 h[4] | (h[5] << 16), h[6] | (h[7] << 16)};
}

// ---- prep (fused): frag-ordered bf16-hi centroids + exact fp32 norms.
// Frag element: lane L of [chunk][ct] block holds C[ct*16+(L&15)][chunk*32+(L>>4)*8+j].
__global__ void pack_centroids(const float* __restrict__ cent,
                               unsigned* __restrict__ cbh,
                               float* __restrict__ cnorm) {
  const int k    = blockIdx.x;   // centroid
  const int lane = threadIdx.x;  // 0..63, dims lane*8..+7
  const float* src = cent + (size_t)k * DIM + lane * 8;
  const float4 a = *(const float4*)src;
  const float4 b = *(const float4*)(src + 4);
  const int chunk = lane >> 2, g = lane & 3;
  ((u32x4*)cbh)[((size_t)chunk * 16 + (k >> 4)) * 64 + g * 16 + (k & 15)] =
      cvt8hi(a, b);
  float s = a.x * a.x + a.y * a.y + a.z * a.z + a.w * a.w +
            b.x * b.x + b.y * b.y + b.z * b.z + b.w * b.w;
#pragma unroll
  for (int off = 32; off > 0; off >>= 1) s += __shfl_down(s, off, 64);
  if (lane == 0) cnorm[k] = s;
}

// ---- main: wave-autonomous, barrier-free. Each wave owns 32 rows end-to-end.
// E frags loaded DIRECTLY from global (coalesced 128B/row-window, prefetched 1
// chunk ahead); C frags streamed from L2-resident frag-ordered cbh. No LDS
// staging, no __syncthreads anywhere.
__global__ __launch_bounds__(256, 2)
void neg_sampler_main(const float* __restrict__ emb,
                      const float* __restrict__ cent,
                      const unsigned* __restrict__ cbh,
                      const float* __restrict__ cnorm,
                      float* __restrict__ out) {
  __shared__ unsigned top4s[4][32][4];  // per-wave private scratch, no barriers

  const int tid  = threadIdx.x;
  const int lane = tid & 63;
  const int w    = tid >> 6;
  const int row0 = (blockIdx.x * 4 + w) * 32;  // this wave's 32 rows
  const int frow = lane & 15, fgrp = lane >> 4;

  f32x4 acc[2][16];
#pragma unroll
  for (int i = 0; i < 2; ++i)
#pragma unroll
    for (int j = 0; j < 16; ++j) acc[i][j] = (f32x4){0.f, 0.f, 0.f, 0.f};

  // A-frag source: lane L covers E[row0 + t*16 + (L&15)][c*32 + (L>>4)*8 .. +7]
  const float* const e0p = emb + (size_t)(row0 + frow) * DIM + fgrp * 8;
  const float* const e1p = e0p + (size_t)16 * DIM;

  float4 a0 = *(const float4*)(e0p);
  float4 b0 = *(const float4*)(e0p + 4);
  float4 a1 = *(const float4*)(e1p);
  float4 b1 = *(const float4*)(e1p + 4);

  for (int c = 0; c < NCHUNK; ++c) {
    // prefetch next-chunk E (HBM latency hides under this chunk's cvt+MFMA)
    const int cn = (c + 1) & (NCHUNK - 1);
    const float4 na0 = *(const float4*)(e0p + cn * 32);
    const float4 nb0 = *(const float4*)(e0p + cn * 32 + 4);
    const float4 na1 = *(const float4*)(e1p + cn * 32);
    const float4 nb1 = *(const float4*)(e1p + cn * 32 + 4);

    // C frags for this chunk: 16 coalesced dwordx4 from L2-hot cbh
    const u32x4* cs = (const u32x4*)cbh + (size_t)c * 1024 + lane;
    u32x4 cc[16];
#pragma unroll
    for (int ct = 0; ct < 16; ++ct) cc[ct] = cs[ct * 64];

    // convert current E to hi/lo frags (VALU overlaps the in-flight loads)
    u32x4 h0, l0, h1, l1;
    split8(a0, b0, h0, l0);
    split8(a1, b1, h1, l1);
    const bf16x8 eh0 = __builtin_bit_cast(bf16x8, h0);
    const bf16x8 el0 = __builtin_bit_cast(bf16x8, l0);
    const bf16x8 eh1 = __builtin_bit_cast(bf16x8, h1);
    const bf16x8 el1 = __builtin_bit_cast(bf16x8, l1);

#pragma unroll
    for (int ct = 0; ct < 16; ++ct) {
      const bf16x8 ch = __builtin_bit_cast(bf16x8, cc[ct]);
      acc[0][ct] = MFMA(eh0, ch, acc[0][ct]);
      acc[1][ct] = MFMA(eh1, ch, acc[1][ct]);
      acc[0][ct] = MFMA(el0, ch, acc[0][ct]);
      acc[1][ct] = MFMA(el1, ch, acc[1][ct]);
    }
    a0 = na0; b0 = nb0; a1 = na1; b1 = nb1;
  }

  // ---- approx top-4 per row. D map: E-row=(lane>>4)*4+reg, cent-col=lane&15.
  const int lcol = lane & 15, lgrp = lane >> 4;
  float cnv[16];
#pragma unroll
  for (int ct = 0; ct < 16; ++ct) cnv[ct] = cnorm[ct * 16 + lcol];

#pragma unroll
  for (int rt = 0; rt < 2; ++rt) {
#pragma unroll
    for (int rg = 0; rg < 4; ++rg) {
      unsigned b0_ = 0xFFFFFFFFu, b1_ = b0_, b2_ = b0_, b3_ = b0_;
      auto ins = [&](unsigned u) {
        b3_ = umin_(b3_, umax_(b2_, u));
        b2_ = umin_(b2_, umax_(b1_, u));
        b1_ = umin_(b1_, umax_(b0_, u));
        b0_ = umin_(b0_, u);
      };
#pragma unroll
      for (int ct = 0; ct < 16; ++ct) {
        const float s = fmaf(-2.f, acc[rt][ct][rg], cnv[ct]);  // ||e||^2 drops
        ins((__float_as_uint(s) & 0xFFFFFF00u) | (unsigned)(ct * 16 + lcol));
      }
#pragma unroll
      for (int off = 1; off < 16; off <<= 1) {  // merge 16 col-lanes of the group
        const unsigned o0 = __shfl_xor(b0_, off, 64);
        const unsigned o1 = __shfl_xor(b1_, off, 64);
        const unsigned o2 = __shfl_xor(b2_, off, 64);
        const unsigned o3 = __shfl_xor(b3_, off, 64);
        ins(o0); ins(o1); ins(o2); ins(o3);
      }
      if (lcol == 0) {
        const int rl = rt * 16 + lgrp * 4 + rg;  // row within wave
        *(u32x4*)&top4s[w][rl][0] = (u32x4){b0_, b1_, b2_, b3_};
      }
    }
  }
  // same-wave ds_write -> ds_read: compiler inserts lgkmcnt, no barrier needed

  // ---- exact fp32 rescore: E row read ONCE (distributed over 64 lanes),
  // 4 candidate dots with interleaved butterfly reduces, exact 2nd-min, gather.
  for (int rr = 0; rr < 32; ++rr) {
    const int grow = row0 + rr;
    const int c0 = (int)(top4s[w][rr][0] & 0xFFu);
    const int c1 = (int)(top4s[w][rr][1] & 0xFFu);
    const int c2 = (int)(top4s[w][rr][2] & 0xFFu);
    const int c3 = (int)(top4s[w][rr][3] & 0xFFu);

    const float4* e4 = (const float4*)(emb + (size_t)grow * DIM) + lane * 2;
    const float4 ev0 = e4[0], ev1 = e4[1];

    auto pdot = [&](int cj) {
      const float4* c4 = (const float4*)(cent + (size_t)cj * DIM) + lane * 2;
      const float4 cv0 = c4[0], cv1 = c4[1];
      float d = ev0.x * cv0.x;
      d = fmaf(ev0.y, cv0.y, d); d = fmaf(ev0.z, cv0.z, d); d = fmaf(ev0.w, cv0.w, d);
      d = fmaf(ev1.x, cv1.x, d); d = fmaf(ev1.y, cv1.y, d);
      d = fmaf(ev1.z, cv1.z, d); d = fmaf(ev1.w, cv1.w, d);
      return d;
    };
    float d0 = pdot(c0), d1 = pdot(c1), d2 = pdot(c2), d3 = pdot(c3);
#pragma unroll
    for (int off = 1; off < 64; off <<= 1) {  // 4 independent chains interleave
      d0 += __shfl_xor(d0, off, 64);
      d1 += __shfl_xor(d1, off, 64);
      d2 += __shfl_xor(d2, off, 64);
      d3 += __shfl_xor(d3, off, 64);
    }
    const float s0 = fmaf(-2.f, d0, cnorm[c0]);
    const float s1 = fmaf(-2.f, d1, cnorm[c1]);
    const float s2 = fmaf(-2.f, d2, cnorm[c2]);
    const float s3 = fmaf(-2.f, d3, cnorm[c3]);

    float v1 = s0, v2 = 3.4e38f;
    int i1 = c0, i2 = K_C;
    auto upd = [&](float s, int ci) {  // stable smaller-index tiebreak
      if (s < v1 || (s == v1 && ci < i1)) { v2 = v1; i2 = i1; v1 = s; i1 = ci; }
      else if (s < v2 || (s == v2 && ci < i2)) { v2 = s; i2 = ci; }
    };
    upd(s1, c1); upd(s2, c2); upd(s3, c3);

    const float4* sp = (const float4*)(cent + (size_t)i2 * DIM) + lane * 2;
    float4* op = (float4*)(out + (size_t)grow * DIM) + lane * 2;
    op[0] = sp[0];
    op[1] = sp[1];
  }
}

extern "C" void kernel_launch(void* const* d_in, const int* in_sizes, int n_in,
                              void* d_out, int out_size, void* d_ws, size_t ws_size,
                              hipStream_t stream) {
  (void)in_sizes; (void)n_in; (void)out_size; (void)ws_size;
  const float* emb  = (const float*)d_in[0];
  const float* cent = (const float*)d_in[1];
  // d_in[2] = batch_id, unused.
  unsigned* cbh = (unsigned*)d_ws;                     // 256 KiB frag-ordered C-hi
  float* cnorm  = (float*)((char*)d_ws + 256 * 1024);  // 1 KiB

  pack_centroids<<<K_C, 64, 0, stream>>>(cent, cbh, cnorm);
  neg_sampler_main<<<N_EMB / 128, 256, 0, stream>>>(emb, cent, cbh, cnorm,
                                                    (float*)d_out);
}

// Round 5
// 320.970 us; speedup vs baseline: 1.0213x; 1.0142x over previous
//
#include <hip/hip_runtime.h>

#define N_EMB 65536
#define DIM   512
#define K_C   256
#define NCHUNK (DIM / 32)
#define RPW   16   // rows per wave
#define WAVES 4

// ws layout: cbh = frag-ordered bf16-hi centroids (256 KiB) | cnorm = float[256] (1 KiB)

typedef __attribute__((ext_vector_type(4))) float        f32x4;
typedef __attribute__((ext_vector_type(8))) __bf16       bf16x8;
typedef __attribute__((ext_vector_type(8))) short        s16x8;
typedef __attribute__((ext_vector_type(4))) unsigned int u32x4;

// ---- MFMA wrapper (rounds 1/2/4 verified). Primary: v8bf16; fallback v8i16.
template <class T>
__device__ inline auto mfma_bf16_t(T a, T b, f32x4 c, int)
    -> decltype(__builtin_amdgcn_mfma_f32_16x16x32_bf16(a, b, c, 0, 0, 0)) {
  return __builtin_amdgcn_mfma_f32_16x16x32_bf16(a, b, c, 0, 0, 0);
}
template <class T>
__device__ inline f32x4 mfma_bf16_t(T a, T b, f32x4 c, long) {
  return __builtin_amdgcn_mfma_f32_16x16x32_bf16(
      __builtin_bit_cast(s16x8, a), __builtin_bit_cast(s16x8, b), c, 0, 0, 0);
}
__device__ inline f32x4 MFMA(bf16x8 a, bf16x8 b, f32x4 c) {
  return mfma_bf16_t(a, b, c, 0);
}

__device__ inline unsigned umin_(unsigned a, unsigned b) { return a < b ? a : b; }
__device__ inline unsigned umax_(unsigned a, unsigned b) { return a > b ? a : b; }

// 8 fp32 -> packed bf16-hi via truncation (compiler folds each pair to v_perm).
// Score error sigma ~0.1 << rank-2..rank-5 gap ~38; exact rescore fixes the rest.
__device__ inline u32x4 pack8hi(const float4 a, const float4 b) {
  return (u32x4){
      (__float_as_uint(a.x) >> 16) | (__float_as_uint(a.y) & 0xFFFF0000u),
      (__float_as_uint(a.z) >> 16) | (__float_as_uint(a.w) & 0xFFFF0000u),
      (__float_as_uint(b.x) >> 16) | (__float_as_uint(b.y) & 0xFFFF0000u),
      (__float_as_uint(b.z) >> 16) | (__float_as_uint(b.w) & 0xFFFF0000u)};
}

__device__ inline u32x4 cvt8hi_rne(const float4 a, const float4 b) {
  float v[8] = {a.x, a.y, a.z, a.w, b.x, b.y, b.z, b.w};
  unsigned h[8];
#pragma unroll
  for (int i = 0; i < 8; ++i) {  // RNE for centroids (prep is cheap, keep quality)
    const unsigned u = __float_as_uint(v[i]);
    h[i] = (u + 0x7FFFu + ((u >> 16) & 1u)) >> 16;
  }
  return (u32x4){h[0] | (h[1] << 16), h[2] | (h[3] << 16),
                 h[4] | (h[5] << 16), h[6] | (h[7] << 16)};
}

// ---- prep (fused): frag-ordered bf16-hi centroids + exact fp32 norms.
// Frag element: lane L of [chunk][ct] block holds C[ct*16+(L&15)][chunk*32+(L>>4)*8+j].
__global__ void pack_centroids(const float* __restrict__ cent,
                               unsigned* __restrict__ cbh,
                               float* __restrict__ cnorm) {
  const int k    = blockIdx.x;   // centroid
  const int lane = threadIdx.x;  // 0..63, dims lane*8..+7
  const float* src = cent + (size_t)k * DIM + lane * 8;
  const float4 a = *(const float4*)src;
  const float4 b = *(const float4*)(src + 4);
  const int chunk = lane >> 2, g = lane & 3;
  ((u32x4*)cbh)[((size_t)chunk * 16 + (k >> 4)) * 64 + g * 16 + (k & 15)] =
      cvt8hi_rne(a, b);
  float s = a.x * a.x + a.y * a.y + a.z * a.z + a.w * a.w +
            b.x * b.x + b.y * b.y + b.z * b.z + b.w * b.w;
#pragma unroll
  for (int off = 32; off > 0; off >>= 1) s += __shfl_down(s, off, 64);
  if (lane == 0) cnorm[k] = s;
}

// ---- main: wave-autonomous, barrier-free; 16 rows/wave so grid = 1024 blocks
// = 4 blocks/CU -> 16 waves/CU (the round-4 bottleneck was 8 waves/CU).
// Pure bf16-hi GEMM (E-lo term dropped: top-4 margin is >100 sigma), approx
// top-4 in registers, exact fp32 rescore + gather.
__global__ __launch_bounds__(256, 4)
void neg_sampler_main(const float* __restrict__ emb,
                      const float* __restrict__ cent,
                      const unsigned* __restrict__ cbh,
                      const float* __restrict__ cnorm,
                      float* __restrict__ out) {
  __shared__ unsigned top4s[WAVES][RPW][4];  // per-wave private, no barriers

  const int tid  = threadIdx.x;
  const int lane = tid & 63;
  const int w    = tid >> 6;
  const int row0 = (blockIdx.x * WAVES + w) * RPW;  // this wave's 16 rows
  const int frow = lane & 15, fgrp = lane >> 4;

  f32x4 acc[16];
#pragma unroll
  for (int j = 0; j < 16; ++j) acc[j] = (f32x4){0.f, 0.f, 0.f, 0.f};

  // A-frag source: lane L covers E[row0 + (L&15)][c*32 + (L>>4)*8 .. +7]
  const float* const ep = emb + (size_t)(row0 + frow) * DIM + fgrp * 8;

  float4 a0 = *(const float4*)(ep);
  float4 b0 = *(const float4*)(ep + 4);

  for (int c = 0; c < NCHUNK; ++c) {
    // prefetch next-chunk E; result needed only next iteration
    const int cn = (c + 1) & (NCHUNK - 1);
    const float4 na = *(const float4*)(ep + cn * 32);
    const float4 nb = *(const float4*)(ep + cn * 32 + 4);

    const bf16x8 eh = __builtin_bit_cast(bf16x8, pack8hi(a0, b0));

    // C frags: two 8-wide windows (keeps VGPR <= 128 for 4 waves/SIMD)
    const u32x4* cs = (const u32x4*)cbh + (size_t)c * 1024 + lane;
    u32x4 cc[8];
#pragma unroll
    for (int ct = 0; ct < 8; ++ct) cc[ct] = cs[ct * 64];
#pragma unroll
    for (int ct = 0; ct < 8; ++ct)
      acc[ct] = MFMA(eh, __builtin_bit_cast(bf16x8, cc[ct]), acc[ct]);
#pragma unroll
    for (int ct = 0; ct < 8; ++ct) cc[ct] = cs[(ct + 8) * 64];
#pragma unroll
    for (int ct = 0; ct < 8; ++ct)
      acc[ct + 8] = MFMA(eh, __builtin_bit_cast(bf16x8, cc[ct]), acc[ct + 8]);

    a0 = na; b0 = nb;
  }

  // ---- approx top-4 per row. D map: E-row=(lane>>4)*4+reg, cent-col=lane&15.
  const int lcol = lane & 15, lgrp = lane >> 4;
  float cnv[16];
#pragma unroll
  for (int ct = 0; ct < 16; ++ct) cnv[ct] = cnorm[ct * 16 + lcol];

#pragma unroll
  for (int rg = 0; rg < 4; ++rg) {
    unsigned b0_ = 0xFFFFFFFFu, b1_ = b0_, b2_ = b0_, b3_ = b0_;
    auto ins = [&](unsigned u) {
      b3_ = umin_(b3_, umax_(b2_, u));
      b2_ = umin_(b2_, umax_(b1_, u));
      b1_ = umin_(b1_, umax_(b0_, u));
      b0_ = umin_(b0_, u);
    };
#pragma unroll
    for (int ct = 0; ct < 16; ++ct) {
      const float s = fmaf(-2.f, acc[ct][rg], cnv[ct]);  // ||e||^2 drops
      ins((__float_as_uint(s) & 0xFFFFFF00u) | (unsigned)(ct * 16 + lcol));
    }
#pragma unroll
    for (int off = 1; off < 16; off <<= 1) {  // merge 16 col-lanes of the group
      const unsigned o0 = __shfl_xor(b0_, off, 64);
      const unsigned o1 = __shfl_xor(b1_, off, 64);
      const unsigned o2 = __shfl_xor(b2_, off, 64);
      const unsigned o3 = __shfl_xor(b3_, off, 64);
      ins(o0); ins(o1); ins(o2); ins(o3);
    }
    if (lcol == 0) {
      const int rl = lgrp * 4 + rg;  // row within wave
      *(u32x4*)&top4s[w][rl][0] = (u32x4){b0_, b1_, b2_, b3_};
    }
  }
  // same-wave ds_write -> ds_read: compiler inserts lgkmcnt, no barrier needed

  // ---- exact fp32 rescore: E row read ONCE (distributed over 64 lanes),
  // 4 candidate dots with interleaved butterfly reduces, exact 2nd-min, gather.
  for (int rr = 0; rr < RPW; ++rr) {
    const int grow = row0 + rr;
    const int c0 = (int)(top4s[w][rr][0] & 0xFFu);
    const int c1 = (int)(top4s[w][rr][1] & 0xFFu);
    const int c2 = (int)(top4s[w][rr][2] & 0xFFu);
    const int c3 = (int)(top4s[w][rr][3] & 0xFFu);

    const float4* e4 = (const float4*)(emb + (size_t)grow * DIM) + lane * 2;
    const float4 ev0 = e4[0], ev1 = e4[1];

    auto pdot = [&](int cj) {
      const float4* c4 = (const float4*)(cent + (size_t)cj * DIM) + lane * 2;
      const float4 cv0 = c4[0], cv1 = c4[1];
      float d = ev0.x * cv0.x;
      d = fmaf(ev0.y, cv0.y, d); d = fmaf(ev0.z, cv0.z, d); d = fmaf(ev0.w, cv0.w, d);
      d = fmaf(ev1.x, cv1.x, d); d = fmaf(ev1.y, cv1.y, d);
      d = fmaf(ev1.z, cv1.z, d); d = fmaf(ev1.w, cv1.w, d);
      return d;
    };
    float d0 = pdot(c0), d1 = pdot(c1), d2 = pdot(c2), d3 = pdot(c3);
#pragma unroll
    for (int off = 1; off < 64; off <<= 1) {  // 4 independent chains interleave
      d0 += __shfl_xor(d0, off, 64);
      d1 += __shfl_xor(d1, off, 64);
      d2 += __shfl_xor(d2, off, 64);
      d3 += __shfl_xor(d3, off, 64);
    }
    const float s0 = fmaf(-2.f, d0, cnorm[c0]);
    const float s1 = fmaf(-2.f, d1, cnorm[c1]);
    const float s2 = fmaf(-2.f, d2, cnorm[c2]);
    const float s3 = fmaf(-2.f, d3, cnorm[c3]);

    float v1 = s0, v2 = 3.4e38f;
    int i1 = c0, i2 = K_C;
    auto upd = [&](float s, int ci) {  // stable smaller-index tiebreak
      if (s < v1 || (s == v1 && ci < i1)) { v2 = v1; i2 = i1; v1 = s; i1 = ci; }
      else if (s < v2 || (s == v2 && ci < i2)) { v2 = s; i2 = ci; }
    };
    upd(s1, c1); upd(s2, c2); upd(s3, c3);

    const float4* sp = (const float4*)(cent + (size_t)i2 * DIM) + lane * 2;
    float4* op = (float4*)(out + (size_t)grow * DIM) + lane * 2;
    op[0] = sp[0];
    op[1] = sp[1];
  }
}

extern "C" void kernel_launch(void* const* d_in, const int* in_sizes, int n_in,
                              void* d_out, int out_size, void* d_ws, size_t ws_size,
                              hipStream_t stream) {
  (void)in_sizes; (void)n_in; (void)out_size; (void)ws_size;
  const float* emb  = (const float*)d_in[0];
  const float* cent = (const float*)d_in[1];
  // d_in[2] = batch_id, unused.
  unsigned* cbh = (unsigned*)d_ws;                     // 256 KiB frag-ordered C-hi
  float* cnorm  = (float*)((char*)d_ws + 256 * 1024);  // 1 KiB

  pack_centroids<<<K_C, 64, 0, stream>>>(cent, cbh, cnorm);
  neg_sampler_main<<<N_EMB / (WAVES * RPW), 256, 0, stream>>>(emb, cent, cbh,
                                                              cnorm, (float*)d_out);
}

// Round 6
// 289.291 us; speedup vs baseline: 1.1332x; 1.1095x over previous
//
#include <hip/hip_runtime.h>

#define N_EMB 65536
#define DIM   512
#define K_C   256
#define NCHUNK (DIM / 32)
#define RPW   16   // rows per wave
#define WAVES 4
#define THETA 1.5f // rescore gate: ~14x the approx-score error sigma (0.11)

// ws layout: cbh = frag-ordered bf16-hi centroids (256 KiB) | cnorm = float[256] (1 KiB)

typedef __attribute__((ext_vector_type(4))) float        f32x4;
typedef __attribute__((ext_vector_type(8))) __bf16       bf16x8;
typedef __attribute__((ext_vector_type(8))) short        s16x8;
typedef __attribute__((ext_vector_type(4))) unsigned int u32x4;

// ---- MFMA wrapper (rounds 1/2/4/5 verified). Primary: v8bf16; fallback v8i16.
template <class T>
__device__ inline auto mfma_bf16_t(T a, T b, f32x4 c, int)
    -> decltype(__builtin_amdgcn_mfma_f32_16x16x32_bf16(a, b, c, 0, 0, 0)) {
  return __builtin_amdgcn_mfma_f32_16x16x32_bf16(a, b, c, 0, 0, 0);
}
template <class T>
__device__ inline f32x4 mfma_bf16_t(T a, T b, f32x4 c, long) {
  return __builtin_amdgcn_mfma_f32_16x16x32_bf16(
      __builtin_bit_cast(s16x8, a), __builtin_bit_cast(s16x8, b), c, 0, 0, 0);
}
__device__ inline f32x4 MFMA(bf16x8 a, bf16x8 b, f32x4 c) {
  return mfma_bf16_t(a, b, c, 0);
}

__device__ inline unsigned umin_(unsigned a, unsigned b) { return a < b ? a : b; }
__device__ inline unsigned umax_(unsigned a, unsigned b) { return a > b ? a : b; }

// 8 fp32 -> packed bf16-hi via truncation (folds to v_perm pairs).
__device__ inline u32x4 pack8hi(const float4 a, const float4 b) {
  return (u32x4){
      (__float_as_uint(a.x) >> 16) | (__float_as_uint(a.y) & 0xFFFF0000u),
      (__float_as_uint(a.z) >> 16) | (__float_as_uint(a.w) & 0xFFFF0000u),
      (__float_as_uint(b.x) >> 16) | (__float_as_uint(b.y) & 0xFFFF0000u),
      (__float_as_uint(b.z) >> 16) | (__float_as_uint(b.w) & 0xFFFF0000u)};
}

__device__ inline u32x4 cvt8hi_rne(const float4 a, const float4 b) {
  float v[8] = {a.x, a.y, a.z, a.w, b.x, b.y, b.z, b.w};
  unsigned h[8];
#pragma unroll
  for (int i = 0; i < 8; ++i) {  // RNE for centroids (prep is cheap, keep quality)
    const unsigned u = __float_as_uint(v[i]);
    h[i] = (u + 0x7FFFu + ((u >> 16) & 1u)) >> 16;
  }
  return (u32x4){h[0] | (h[1] << 16), h[2] | (h[3] << 16),
                 h[4] | (h[5] << 16), h[6] | (h[7] << 16)};
}

// ---- prep (fused): frag-ordered bf16-hi centroids + exact fp32 norms.
// Frag element: lane L of [chunk][ct] block holds C[ct*16+(L&15)][chunk*32+(L>>4)*8+j].
__global__ void pack_centroids(const float* __restrict__ cent,
                               unsigned* __restrict__ cbh,
                               float* __restrict__ cnorm) {
  const int k    = blockIdx.x;   // centroid
  const int lane = threadIdx.x;  // 0..63, dims lane*8..+7
  const float* src = cent + (size_t)k * DIM + lane * 8;
  const float4 a = *(const float4*)src;
  const float4 b = *(const float4*)(src + 4);
  const int chunk = lane >> 2, g = lane & 3;
  ((u32x4*)cbh)[((size_t)chunk * 16 + (k >> 4)) * 64 + g * 16 + (k & 15)] =
      cvt8hi_rne(a, b);
  float s = a.x * a.x + a.y * a.y + a.z * a.z + a.w * a.w +
            b.x * b.x + b.y * b.y + b.z * b.z + b.w * b.w;
#pragma unroll
  for (int off = 32; off > 0; off >>= 1) s += __shfl_down(s, off, 64);
  if (lane == 0) cnorm[k] = s;
}

// ---- main: wave-autonomous, barrier-free, MLP-first.
// GEMM: C-frags double-buffered one half-chunk ahead in registers (L2 latency
// off the critical path); E prefetched one chunk ahead. Selection: theta-gated
// (exact fp32 rescore only when approx gaps < THETA, ~20% of rows). Gather
// with 1-row lookahead.
__global__ __launch_bounds__(256, 3)
void neg_sampler_main(const float* __restrict__ emb,
                      const float* __restrict__ cent,
                      const unsigned* __restrict__ cbh,
                      const float* __restrict__ cnorm,
                      float* __restrict__ out) {
  __shared__ unsigned top4s[WAVES][RPW][4];  // per-wave private, no barriers

  const int tid  = threadIdx.x;
  const int lane = tid & 63;
  const int w    = tid >> 6;
  const int row0 = (blockIdx.x * WAVES + w) * RPW;  // this wave's 16 rows
  const int frow = lane & 15, fgrp = lane >> 4;

  f32x4 acc[16];
#pragma unroll
  for (int j = 0; j < 16; ++j) acc[j] = (f32x4){0.f, 0.f, 0.f, 0.f};

  // A-frag source: lane L covers E[row0 + (L&15)][c*32 + (L>>4)*8 .. +7]
  const float* const ep = emb + (size_t)(row0 + frow) * DIM + fgrp * 8;
  float4 ea = *(const float4*)(ep);
  float4 eb = *(const float4*)(ep + 4);

  // Rolling C double-buffer: A = current half-chunk (8 frags), B = next.
  const u32x4* const cs = (const u32x4*)cbh + lane;
  u32x4 A[8], B[8];
#pragma unroll
  for (int i = 0; i < 8; ++i) A[i] = cs[i * 64];
#pragma unroll
  for (int i = 0; i < 8; ++i) B[i] = cs[512 + i * 64];

  for (int c = 0; c < NCHUNK; ++c) {
    const int cn = (c + 1) & (NCHUNK - 1);
    const float4 na = *(const float4*)(ep + cn * 32);      // E chunk c+1
    const float4 nb = *(const float4*)(ep + cn * 32 + 4);
    const bf16x8 eh = __builtin_bit_cast(bf16x8, pack8hi(ea, eb));

#pragma unroll
    for (int i = 0; i < 8; ++i)
      acc[i] = MFMA(eh, __builtin_bit_cast(bf16x8, A[i]), acc[i]);
    const u32x4* const csn = cs + (size_t)cn * 1024;       // refill A <- (c+1,h0)
#pragma unroll
    for (int i = 0; i < 8; ++i) A[i] = csn[i * 64];

#pragma unroll
    for (int i = 0; i < 8; ++i)
      acc[8 + i] = MFMA(eh, __builtin_bit_cast(bf16x8, B[i]), acc[8 + i]);
#pragma unroll
    for (int i = 0; i < 8; ++i) B[i] = csn[512 + i * 64];  // refill B <- (c+1,h1)

    ea = na; eb = nb;
  }

  // ---- approx top-4 per row. D map: E-row=(lane>>4)*4+reg, cent-col=lane&15.
  const int lcol = lane & 15, lgrp = lane >> 4;
  float cnv[16];
#pragma unroll
  for (int ct = 0; ct < 16; ++ct) cnv[ct] = cnorm[ct * 16 + lcol];

#pragma unroll
  for (int rg = 0; rg < 4; ++rg) {
    unsigned b0_ = 0xFFFFFFFFu, b1_ = b0_, b2_ = b0_, b3_ = b0_;
    auto ins = [&](unsigned u) {
      b3_ = umin_(b3_, umax_(b2_, u));
      b2_ = umin_(b2_, umax_(b1_, u));
      b1_ = umin_(b1_, umax_(b0_, u));
      b0_ = umin_(b0_, u);
    };
#pragma unroll
    for (int ct = 0; ct < 16; ++ct) {
      const float s = fmaf(-2.f, acc[ct][rg], cnv[ct]);  // ||e||^2 drops
      ins((__float_as_uint(s) & 0xFFFFFF00u) | (unsigned)(ct * 16 + lcol));
    }
#pragma unroll
    for (int off = 1; off < 16; off <<= 1) {  // merge 16 col-lanes of the group
      const unsigned o0 = __shfl_xor(b0_, off, 64);
      const unsigned o1 = __shfl_xor(b1_, off, 64);
      const unsigned o2 = __shfl_xor(b2_, off, 64);
      const unsigned o3 = __shfl_xor(b3_, off, 64);
      ins(o0); ins(o1); ins(o2); ins(o3);
    }
    if (lcol == 0) {
      const int rl = lgrp * 4 + rg;  // row within wave
      *(u32x4*)&top4s[w][rl][0] = (u32x4){b0_, b1_, b2_, b3_};
    }
  }
  // same-wave ds_write -> ds_read: compiler inserts lgkmcnt, no barrier needed

  // ---- selection: theta-gate. If approx gaps certify rank-2, take it; else
  // exact fp32 rescore (round-5 path). Result index stored in slot 3.
  for (int rr = 0; rr < RPW; ++rr) {
    const unsigned u0 = top4s[w][rr][0], u1 = top4s[w][rr][1];
    const unsigned u2 = top4s[w][rr][2], u3 = top4s[w][rr][3];
    const float a0s = __uint_as_float(u0 & 0xFFFFFF00u);
    const float a1s = __uint_as_float(u1 & 0xFFFFFF00u);
    const float a2s = __uint_as_float(u2 & 0xFFFFFF00u);
    int i2;
    if (a1s - a0s >= THETA && a2s - a1s >= THETA) {
      i2 = (int)(u1 & 0xFFu);  // provably the true 2nd-nearest
    } else {
      const int grow = row0 + rr;
      const int c0 = (int)(u0 & 0xFFu), c1 = (int)(u1 & 0xFFu);
      const int c2 = (int)(u2 & 0xFFu), c3 = (int)(u3 & 0xFFu);

      const float4* e4 = (const float4*)(emb + (size_t)grow * DIM) + lane * 2;
      const float4 ev0 = e4[0], ev1 = e4[1];

      auto pdot = [&](int cj) {
        const float4* c4 = (const float4*)(cent + (size_t)cj * DIM) + lane * 2;
        const float4 cv0 = c4[0], cv1 = c4[1];
        float d = ev0.x * cv0.x;
        d = fmaf(ev0.y, cv0.y, d); d = fmaf(ev0.z, cv0.z, d);
        d = fmaf(ev0.w, cv0.w, d);
        d = fmaf(ev1.x, cv1.x, d); d = fmaf(ev1.y, cv1.y, d);
        d = fmaf(ev1.z, cv1.z, d); d = fmaf(ev1.w, cv1.w, d);
        return d;
      };
      float d0 = pdot(c0), d1 = pdot(c1), d2 = pdot(c2), d3 = pdot(c3);
#pragma unroll
      for (int off = 1; off < 64; off <<= 1) {  // 4 independent chains
        d0 += __shfl_xor(d0, off, 64);
        d1 += __shfl_xor(d1, off, 64);
        d2 += __shfl_xor(d2, off, 64);
        d3 += __shfl_xor(d3, off, 64);
      }
      const float s0 = fmaf(-2.f, d0, cnorm[c0]);
      const float s1 = fmaf(-2.f, d1, cnorm[c1]);
      const float s2 = fmaf(-2.f, d2, cnorm[c2]);
      const float s3 = fmaf(-2.f, d3, cnorm[c3]);

      float v1 = s0, v2 = 3.4e38f;
      int i1 = c0; i2 = K_C;
      auto upd = [&](float s, int ci) {  // stable smaller-index tiebreak
        if (s < v1 || (s == v1 && ci < i1)) { v2 = v1; i2 = i1; v1 = s; i1 = ci; }
        else if (s < v2 || (s == v2 && ci < i2)) { v2 = s; i2 = ci; }
      };
      upd(s1, c1); upd(s2, c2); upd(s3, c3);
    }
    if (lane == 0) top4s[w][rr][3] = (unsigned)i2;
  }

  // ---- gather with 1-row lookahead (cent-row load pipelines over the store)
  unsigned nid = top4s[w][0][3];
  const float4* sp = (const float4*)(cent + (size_t)nid * DIM) + lane * 2;
  float4 g0 = sp[0], g1 = sp[1];
  for (int rr = 0; rr < RPW; ++rr) {
    const float4 o0 = g0, o1 = g1;
    if (rr + 1 < RPW) {
      nid = top4s[w][rr + 1][3];
      sp = (const float4*)(cent + (size_t)nid * DIM) + lane * 2;
      g0 = sp[0]; g1 = sp[1];
    }
    float4* op = (float4*)(out + (size_t)(row0 + rr) * DIM) + lane * 2;
    op[0] = o0;
    op[1] = o1;
  }
}

extern "C" void kernel_launch(void* const* d_in, const int* in_sizes, int n_in,
                              void* d_out, int out_size, void* d_ws, size_t ws_size,
                              hipStream_t stream) {
  (void)in_sizes; (void)n_in; (void)out_size; (void)ws_size;
  const float* emb  = (const float*)d_in[0];
  const float* cent = (const float*)d_in[1];
  // d_in[2] = batch_id, unused.
  unsigned* cbh = (unsigned*)d_ws;                     // 256 KiB frag-ordered C-hi
  float* cnorm  = (float*)((char*)d_ws + 256 * 1024);  // 1 KiB

  pack_centroids<<<K_C, 64, 0, stream>>>(cent, cbh, cnorm);
  neg_sampler_main<<<N_EMB / (WAVES * RPW), 256, 0, stream>>>(emb, cent, cbh,
                                                              cnorm, (float*)d_out);
}